// Round 9
// baseline (175.654 us; speedup 1.0000x reference)
//
#include <hip/hip_runtime.h>
#include <math.h>

typedef __bf16 bf16x8 __attribute__((ext_vector_type(8)));
typedef __bf16 bf16x4 __attribute__((ext_vector_type(4)));
typedef float f32x4 __attribute__((ext_vector_type(4)));

constexpr int Bb = 2, Tt = 2048, Ee = 1024, Hh = 16, Hs = 64;
constexpr int Mm = Bb * Tt;  // 4096

__device__ inline unsigned short f2bf(float f) {
    union { float f; unsigned u; } c; c.f = f;
    unsigned u = c.u;
    u += 0x7FFFu + ((u >> 16) & 1u);   // RNE
    return (unsigned short)(u >> 16);
}

__device__ inline void gl2lds16(const void* g, void* l) {
    __builtin_amdgcn_global_load_lds(
        (const __attribute__((address_space(1))) void*)g,
        (__attribute__((address_space(3))) void*)l, 16, 0, 0);
}

// pack two positive f32 into one dword of bf16 pair {hi=a, lo=b}, round-half-up
__device__ inline unsigned pk_bf16(float a, float b) {
    union { float f; unsigned u; } ca, cb;
    ca.f = a; cb.f = b;
    return __builtin_amdgcn_perm(ca.u + 0x8000u, cb.u + 0x8000u, 0x07060302u);
}

// ---------------------------------------------------------------------------
// prep: z<4 -> transpose weight z (f32 [K][N] -> bf16 [N][K]);
//       z==4 -> cast x to bf16
// ---------------------------------------------------------------------------
__global__ __launch_bounds__(256) void prep(const float* __restrict__ x,
                                            const float* __restrict__ Wq,
                                            const float* __restrict__ Wk,
                                            const float* __restrict__ Wv,
                                            const float* __restrict__ Wp,
                                            unsigned short* __restrict__ xb,
                                            unsigned short* __restrict__ wt3,
                                            unsigned short* __restrict__ wpt) {
    const int tid = threadIdx.x;
    if (blockIdx.z == 4) {
        int flat = (blockIdx.y * 16 + blockIdx.x) * 256 + tid;
#pragma unroll
        for (int i = 0; i < 16; i++) {
            int gid = flat + i * 65536;
            float4 v = ((const float4*)x)[gid];
            ushort4 o;
            o.x = f2bf(v.x); o.y = f2bf(v.y); o.z = f2bf(v.z); o.w = f2bf(v.w);
            ((ushort4*)xb)[gid] = o;
        }
        return;
    }
    __shared__ unsigned short t[64][68];
    const float* W = (blockIdx.z == 0) ? Wq : (blockIdx.z == 1) ? Wk
                    : (blockIdx.z == 2) ? Wv : Wp;
    unsigned short* dst = (blockIdx.z < 3) ? wt3 + (size_t)blockIdx.z * 1024 * 1024 : wpt;
    const int k0 = blockIdx.x * 64, n0 = blockIdx.y * 64;
#pragma unroll
    for (int j = 0; j < 4; j++) {
        int row = (tid >> 4) + j * 16;
        int c4 = (tid & 15) * 4;
        float4 v = *(const float4*)&W[(size_t)(k0 + row) * 1024 + n0 + c4];
        t[row][c4 + 0] = f2bf(v.x); t[row][c4 + 1] = f2bf(v.y);
        t[row][c4 + 2] = f2bf(v.z); t[row][c4 + 3] = f2bf(v.w);
    }
    __syncthreads();
#pragma unroll
    for (int j = 0; j < 16; j++) {
        int flat = j * 256 + tid;
        int orow = flat >> 6, ocol = flat & 63;
        dst[(size_t)(n0 + orow) * 1024 + k0 + ocol] = t[ocol][orow];
    }
}

// ---------------------------------------------------------------------------
// Shared 128x128 / BK=32 bf16 MFMA main loop (m97 structure)
// ---------------------------------------------------------------------------
__device__ inline void gemm_mainloop(const unsigned short* __restrict__ A,
                                     const unsigned short* __restrict__ Bt,
                                     unsigned short* As, unsigned short* Bs,
                                     int bm, int bn, int tid, f32x4 (&acc)[4][4]) {
    const int lane = tid & 63, w = tid >> 6;
    const int quad = lane >> 4, cl = lane & 15;
    const int wm = (w >> 1) * 64, wn = (w & 1) * 64;

    auto stage = [&](int k0) {
#pragma unroll
        for (int i = 0; i < 2; i++) {
            int L = tid + i * 256;
            int r = L >> 2;
            int kc = (L & 3) ^ (r & 3);
            gl2lds16(A + (size_t)(bm + r) * 1024 + k0 + kc * 8, &As[L * 8]);
        }
#pragma unroll
        for (int i = 0; i < 2; i++) {
            int L = tid + i * 256;
            int r = L >> 2;
            int kc = (L & 3) ^ (r & 3);
            gl2lds16(Bt + (size_t)(bn + r) * 1024 + k0 + kc * 8, &Bs[L * 8]);
        }
    };

    stage(0);
    __syncthreads();
    for (int k0 = 0;;) {
        bf16x8 af[4], bfr[4];
#pragma unroll
        for (int mt = 0; mt < 4; mt++) {
            int r = wm + mt * 16 + cl;
            af[mt] = *(const bf16x8*)&As[(r * 4 + (quad ^ (r & 3))) * 8];
            int rb = wn + mt * 16 + cl;
            bfr[mt] = *(const bf16x8*)&Bs[(rb * 4 + (quad ^ (rb & 3))) * 8];
        }
#pragma unroll
        for (int mt = 0; mt < 4; mt++)
#pragma unroll
            for (int nt = 0; nt < 4; nt++)
                acc[mt][nt] = __builtin_amdgcn_mfma_f32_16x16x32_bf16(
                    af[mt], bfr[nt], acc[mt][nt], 0, 0, 0);
        k0 += 32;
        if (k0 >= 1024) break;
        __syncthreads();
        stage(k0);
        __syncthreads();
    }
}

// ---------------------------------------------------------------------------
// Fused QKV projection: D[4096, 3072] = xb * wt3^T. Q epilogue folds the
// softmax scale (1/32)*log2(e).
// ---------------------------------------------------------------------------
__global__ __launch_bounds__(256, 2) void gemm_qkv(const unsigned short* __restrict__ A,
                                                   const unsigned short* __restrict__ Bt,
                                                   unsigned short* __restrict__ qb,
                                                   unsigned short* __restrict__ kb,
                                                   unsigned short* __restrict__ vtb) {
    __shared__ unsigned short As[128 * 32];
    __shared__ unsigned short Bs[128 * 32];
    const int tid = threadIdx.x;
    const int bm = blockIdx.y * 128;
    const int bn = blockIdx.x * 128;
    f32x4 acc[4][4] = {};
    gemm_mainloop(A, Bt, As, Bs, bm, bn, tid, acc);

    const int lane = tid & 63, w = tid >> 6;
    const int quad = lane >> 4, cl = lane & 15;
    const int wm = (w >> 1) * 64, wn = (w & 1) * 64;
    const int region = bn >> 10;

    if (region < 2) {
        unsigned short* dst = region ? kb : qb;
        const float qs = region ? 1.0f : 0.045084220027780107f;  // (1/32)*log2e
#pragma unroll
        for (int mt = 0; mt < 4; mt++)
#pragma unroll
            for (int nt = 0; nt < 4; nt++)
#pragma unroll
                for (int rg = 0; rg < 4; rg++) {
                    int m = bm + wm + mt * 16 + quad * 4 + rg;
                    int nn = (bn + wn + nt * 16 + cl) & 1023;
                    int b = m >> 11, t = m & 2047, h = nn >> 6, hs = nn & 63;
                    dst[((size_t)(b * 16 + h) * 2048 + t) * 64 + hs] =
                        f2bf(acc[mt][nt][rg] * qs);
                }
    } else {
#pragma unroll
        for (int mt = 0; mt < 4; mt++) {
            int m0 = bm + wm + mt * 16 + quad * 4;
            int b = m0 >> 11, t0 = m0 & 2047;
#pragma unroll
            for (int nt = 0; nt < 4; nt++) {
                int nn = (bn + wn + nt * 16 + cl) & 1023;
                int h = nn >> 6, hs = nn & 63;
                ushort4 pk;
                pk.x = f2bf(acc[mt][nt][0]); pk.y = f2bf(acc[mt][nt][1]);
                pk.z = f2bf(acc[mt][nt][2]); pk.w = f2bf(acc[mt][nt][3]);
                *(ushort4*)&vtb[((size_t)(b * 16 + h) * 64 + hs) * 2048 + t0] = pk;
            }
        }
    }
}

// ---------------------------------------------------------------------------
// Final projection: out[4096,1024] fp32 = ab * wpt^T + bias. 64x128 tiles.
// ---------------------------------------------------------------------------
__global__ __launch_bounds__(256, 4) void gemm_out(const unsigned short* __restrict__ A,
                                                   const unsigned short* __restrict__ Bt,
                                                   const float* __restrict__ bias,
                                                   float* __restrict__ out) {
    __shared__ unsigned short As[64 * 32];   // 4 KB
    __shared__ unsigned short Bs[128 * 32];  // 8 KB
    const int tid = threadIdx.x;
    const int bm = blockIdx.y * 64;
    const int bn = blockIdx.x * 128;
    const int lane = tid & 63, w = tid >> 6;
    const int quad = lane >> 4, cl = lane & 15;
    const int wm = (w >> 1) * 32, wn = (w & 1) * 64;
    f32x4 acc[2][4] = {};

    auto stage = [&](int k0) {
        {
            int L = tid;
            int r = L >> 2;
            int kc = (L & 3) ^ (r & 3);
            gl2lds16(A + (size_t)(bm + r) * 1024 + k0 + kc * 8, &As[L * 8]);
        }
#pragma unroll
        for (int i = 0; i < 2; i++) {
            int L = tid + i * 256;
            int r = L >> 2;
            int kc = (L & 3) ^ (r & 3);
            gl2lds16(Bt + (size_t)(bn + r) * 1024 + k0 + kc * 8, &Bs[L * 8]);
        }
    };

    stage(0);
    __syncthreads();
    for (int k0 = 0;;) {
        bf16x8 af[2], bfr[4];
#pragma unroll
        for (int mt = 0; mt < 2; mt++) {
            int r = wm + mt * 16 + cl;
            af[mt] = *(const bf16x8*)&As[(r * 4 + (quad ^ (r & 3))) * 8];
        }
#pragma unroll
        for (int nt = 0; nt < 4; nt++) {
            int rb = wn + nt * 16 + cl;
            bfr[nt] = *(const bf16x8*)&Bs[(rb * 4 + (quad ^ (rb & 3))) * 8];
        }
#pragma unroll
        for (int mt = 0; mt < 2; mt++)
#pragma unroll
            for (int nt = 0; nt < 4; nt++)
                acc[mt][nt] = __builtin_amdgcn_mfma_f32_16x16x32_bf16(
                    af[mt], bfr[nt], acc[mt][nt], 0, 0, 0);
        k0 += 32;
        if (k0 >= 1024) break;
        __syncthreads();
        stage(k0);
        __syncthreads();
    }

#pragma unroll
    for (int mt = 0; mt < 2; mt++)
#pragma unroll
        for (int nt = 0; nt < 4; nt++)
#pragma unroll
            for (int rg = 0; rg < 4; rg++) {
                int m = bm + wm + mt * 16 + quad * 4 + rg;
                int n = bn + wn + nt * 16 + cl;
                out[(size_t)m * 1024 + n] = acc[mt][nt][rg] + bias[n];
            }
}

// ---------------------------------------------------------------------------
// MFMA flash attention v3: transposed-S, key-parity split, 2-pass PV,
// perm-packed P, 40KB LDS -> 4 blocks/CU.
// Block = 4 waves = 64 q-rows. Wave w: parity p=w>>1 (even/odd k-tiles),
// qhalf=w&1 (32 q-rows). Fixed-max softmax (additive partials; pair merge
// through dead K/V LDS). Q pre-scaled by (1/32)log2e in gemm_qkv.
// P slice per wave = 32q x 32k (2KB), two k-passes; write->read same-wave
// LDS is in-order. Swizzle chunk^((row>>1)&3) gives <=2-way banks (free).
// LDS layout (shorts): K0 0 | V0 4096 | K1 8192 | V1 12288 | P 16384+w*1024
// ---------------------------------------------------------------------------
__global__ __launch_bounds__(256, 4) void attn_mfma(const unsigned short* __restrict__ qg,
                                                    const unsigned short* __restrict__ kg,
                                                    const unsigned short* __restrict__ vtg,
                                                    unsigned short* __restrict__ og) {
    __shared__ unsigned short lds[20480];  // 40 KB
    float* Cmb = (float*)lds;              // combine O: [64][stride 68] f32 (dead KV)
    float* Ll = (float*)(lds + 8704);      // combine l: 64 f32 (dead KV)

    const int tid = threadIdx.x;
    const int idx = blockIdx.x;
    const int bh = idx & 31;
    const int qt = 31 - (idx >> 5);        // 64-row q-tile, longest first
    const int lane = tid & 63, w = tid >> 6;
    const int quad = lane >> 4, cl = lane & 15;
    const int p = w >> 1;                  // k-tile parity this wave handles
    const int qhalf = w & 1;               // which 32 q-rows
    const int qbase = qt * 64;
    const unsigned short* qB = qg + (size_t)bh * 2048 * 64;
    const unsigned short* kB = kg + (size_t)bh * 2048 * 64;
    const unsigned short* vB = vtg + (size_t)bh * 64 * 2048;

    auto stageKV = [&](int kt, int buf) {
        unsigned short* Kd = lds + buf * 8192;
        unsigned short* Vd = lds + 4096 + buf * 8192;
#pragma unroll
        for (int i = 0; i < 2; i++) {
            int L = tid + i * 256;
            int r = L >> 3;
            int kc = (L & 7) ^ (r & 7);
            gl2lds16(kB + (size_t)(kt * 64 + r) * 64 + kc * 8, &Kd[L * 8]);
            gl2lds16(vB + (size_t)r * 2048 + kt * 64 + kc * 8, &Vd[L * 8]);
        }
    };

    // Q fragments straight from global (B-operand layout; 16B loads)
    bf16x8 qf[2][2];
#pragma unroll
    for (int nt2 = 0; nt2 < 2; nt2++)
#pragma unroll
        for (int kf = 0; kf < 2; kf++) {
            int row = qbase + qhalf * 32 + nt2 * 16 + cl;
            qf[nt2][kf] = *(const bf16x8*)&qB[(size_t)row * 64 + (kf * 4 + quad) * 8];
        }

    bf16x8 ones;
#pragma unroll
    for (int i = 0; i < 8; i++) ones[i] = (__bf16)1.0f;

    f32x4 oacc[2][4] = {};
    f32x4 lacc[2] = {};
    unsigned short* Pw = lds + 16384 + w * 1024;  // 32q x 32k per pass
    const unsigned short* Kl = lds + p * 8192;
    const unsigned short* Vl = lds + 4096 + p * 8192;
    const int nit = (qt + 2) >> 1;

    for (int i = 0; i < nit; i++) {
        stageKV(2 * i, 0);
        if (2 * i + 1 <= qt) stageKV(2 * i + 1, 1);
        __syncthreads();

        const int kt = 2 * i + p;
        if (kt <= qt) {
            const bool diag = (kt == qt);
            // ---- S^T = K Q^T : rows = 64 keys, cols = 32 q ----
            f32x4 sac[4][2] = {};
#pragma unroll
            for (int kf = 0; kf < 2; kf++)
#pragma unroll
                for (int mt = 0; mt < 4; mt++) {
                    int r = mt * 16 + cl, cc = kf * 4 + quad;
                    bf16x8 kf8 = *(const bf16x8*)&Kl[(r * 8 + (cc ^ (r & 7))) * 8];
#pragma unroll
                    for (int nt2 = 0; nt2 < 2; nt2++)
                        sac[mt][nt2] = __builtin_amdgcn_mfma_f32_16x16x32_bf16(
                            kf8, qf[nt2][kf], sac[mt][nt2], 0, 0, 0);
                }
            // ---- two passes of 32 keys: exp2 + perm-pack P, then PV ----
#pragma unroll
            for (int ks = 0; ks < 2; ks++) {
                // exp2 + pack + P write (b64, swizzled, <=2-way banks)
#pragma unroll
                for (int mtl = 0; mtl < 2; mtl++)
#pragma unroll
                    for (int nt2 = 0; nt2 < 2; nt2++) {
                        float pv[4];
#pragma unroll
                        for (int rg = 0; rg < 4; rg++) {
                            float e = exp2f(sac[ks * 2 + mtl][nt2][rg]);
                            if (diag && (ks * 32 + mtl * 16 + quad * 4 + rg >
                                         nt2 * 16 + cl + qhalf * 32))
                                e = 0.0f;
                            pv[rg] = e;
                        }
                        uint2 d;
                        d.x = pk_bf16(pv[1], pv[0]);  // lo dword: keys +0,+1
                        d.y = pk_bf16(pv[3], pv[2]);  // hi dword: keys +2,+3
                        int r2 = nt2 * 16 + cl;
                        int c = mtl * 2 + (quad >> 1);
                        int pc = c ^ ((r2 >> 1) & 3);
                        *(uint2*)&Pw[r2 * 32 + pc * 8 + (quad & 1) * 4] = d;
                    }
                // PV: O += P V ; l += P.1   (k = 32 keys of this pass)
                bf16x8 pf[2];
#pragma unroll
                for (int mt2 = 0; mt2 < 2; mt2++) {
                    int r2 = mt2 * 16 + cl;
                    int pc = quad ^ ((r2 >> 1) & 3);
                    pf[mt2] = *(const bf16x8*)&Pw[r2 * 32 + pc * 8];
                }
#pragma unroll
                for (int mt2 = 0; mt2 < 2; mt2++)
                    lacc[mt2] = __builtin_amdgcn_mfma_f32_16x16x32_bf16(
                        pf[mt2], ones, lacc[mt2], 0, 0, 0);
#pragma unroll
                for (int nt = 0; nt < 4; nt++) {
                    int r = nt * 16 + cl, cc = ks * 4 + quad;
                    bf16x8 vf = *(const bf16x8*)&Vl[(r * 8 + (cc ^ (r & 7))) * 8];
#pragma unroll
                    for (int mt2 = 0; mt2 < 2; mt2++)
                        oacc[mt2][nt] = __builtin_amdgcn_mfma_f32_16x16x32_bf16(
                            pf[mt2], vf, oacc[mt2][nt], 0, 0, 0);
                }
            }
        }
        __syncthreads();
    }

    // ---- pair combine: p=1 writes partials to dead K/V LDS, p=0 adds ----
    if (p == 1) {
#pragma unroll
        for (int mt2 = 0; mt2 < 2; mt2++)
#pragma unroll
            for (int rg = 0; rg < 4; rg++) {
                int row = qhalf * 32 + mt2 * 16 + quad * 4 + rg;
                if (cl == 0) Ll[row] = lacc[mt2][rg];
#pragma unroll
                for (int nt = 0; nt < 4; nt++)
                    Cmb[row * 68 + nt * 16 + cl] = oacc[mt2][nt][rg];
            }
    }
    __syncthreads();
    if (p == 0) {
        const int b = bh >> 4, h = bh & 15;
#pragma unroll
        for (int mt2 = 0; mt2 < 2; mt2++)
#pragma unroll
            for (int rg = 0; rg < 4; rg++) {
                int row = qhalf * 32 + mt2 * 16 + quad * 4 + rg;
                float inv = 1.0f / (lacc[mt2][rg] + Ll[row]);
                int t = qbase + row;
#pragma unroll
                for (int nt = 0; nt < 4; nt++) {
                    int hs = nt * 16 + cl;
                    float val = oacc[mt2][nt][rg] + Cmb[row * 68 + nt * 16 + cl];
                    og[((size_t)(b * 2048 + t)) * 1024 + h * 64 + hs] = f2bf(val * inv);
                }
            }
    }
}

// ---------------------------------------------------------------------------
extern "C" void kernel_launch(void* const* d_in, const int* in_sizes, int n_in,
                              void* d_out, int out_size, void* d_ws, size_t ws_size,
                              hipStream_t stream) {
    const float* x = (const float*)d_in[0];
    const float* Wq = (const float*)d_in[1];
    const float* Wk = (const float*)d_in[2];
    const float* Wv = (const float*)d_in[3];
    const float* Wp = (const float*)d_in[4];
    const float* bp = (const float*)d_in[5];
    float* out = (float*)d_out;

    unsigned short* xb = (unsigned short*)d_ws;      // 8 MB
    unsigned short* wt3 = xb + (size_t)Mm * Ee;      // 6 MB (Q,K,V transposed)
    unsigned short* wpt = wt3 + (size_t)3 * Ee * Ee; // 2 MB
    unsigned short* qb = wpt + (size_t)Ee * Ee;      // 8 MB each
    unsigned short* kb = qb + (size_t)Mm * Ee;
    unsigned short* vtb = kb + (size_t)Mm * Ee;
    unsigned short* ab = vtb + (size_t)Mm * Ee;

    prep<<<dim3(16, 16, 5), dim3(256), 0, stream>>>(x, Wq, Wk, Wv, Wp, xb, wt3, wpt);
    gemm_qkv<<<dim3(24, 32), dim3(256), 0, stream>>>(xb, wt3, qb, kb, vtb);
    attn_mfma<<<dim3(1024), dim3(256), 0, stream>>>(qb, kb, vtb, ab);
    gemm_out<<<dim3(8, 64), dim3(256), 0, stream>>>(ab, wpt, bp, out);
}

// Round 10
// 169.871 us; speedup vs baseline: 1.0340x; 1.0340x over previous
//
#include <hip/hip_runtime.h>
#include <math.h>

typedef __bf16 bf16x8 __attribute__((ext_vector_type(8)));
typedef __bf16 bf16x4 __attribute__((ext_vector_type(4)));
typedef float f32x4 __attribute__((ext_vector_type(4)));

constexpr int Bb = 2, Tt = 2048, Ee = 1024, Hh = 16, Hs = 64;
constexpr int Mm = Bb * Tt;  // 4096

__device__ inline unsigned short f2bf(float f) {
    union { float f; unsigned u; } c; c.f = f;
    unsigned u = c.u;
    u += 0x7FFFu + ((u >> 16) & 1u);   // RNE
    return (unsigned short)(u >> 16);
}

#if __has_builtin(__builtin_amdgcn_exp2f)
#define EXP2(x) __builtin_amdgcn_exp2f(x)
#else
#define EXP2(x) exp2f(x)
#endif

__device__ inline void gl2lds16(const void* g, void* l) {
    __builtin_amdgcn_global_load_lds(
        (const __attribute__((address_space(1))) void*)g,
        (__attribute__((address_space(3))) void*)l, 16, 0, 0);
}

// pack two positive f32 into one dword of bf16 pair {hi=a, lo=b}, round-half-up
__device__ inline unsigned pk_bf16(float a, float b) {
    union { float f; unsigned u; } ca, cb;
    ca.f = a; cb.f = b;
    return __builtin_amdgcn_perm(ca.u + 0x8000u, cb.u + 0x8000u, 0x07060302u);
}

// ---------------------------------------------------------------------------
// prep: z<4 -> transpose weight z (f32 [K][N] -> bf16 [N][K]);
//       z==4 -> cast x to bf16
// ---------------------------------------------------------------------------
__global__ __launch_bounds__(256) void prep(const float* __restrict__ x,
                                            const float* __restrict__ Wq,
                                            const float* __restrict__ Wk,
                                            const float* __restrict__ Wv,
                                            const float* __restrict__ Wp,
                                            unsigned short* __restrict__ xb,
                                            unsigned short* __restrict__ wt3,
                                            unsigned short* __restrict__ wpt) {
    const int tid = threadIdx.x;
    if (blockIdx.z == 4) {
        int flat = (blockIdx.y * 16 + blockIdx.x) * 256 + tid;
#pragma unroll
        for (int i = 0; i < 16; i++) {
            int gid = flat + i * 65536;
            float4 v = ((const float4*)x)[gid];
            ushort4 o;
            o.x = f2bf(v.x); o.y = f2bf(v.y); o.z = f2bf(v.z); o.w = f2bf(v.w);
            ((ushort4*)xb)[gid] = o;
        }
        return;
    }
    __shared__ unsigned short t[64][68];
    const float* W = (blockIdx.z == 0) ? Wq : (blockIdx.z == 1) ? Wk
                    : (blockIdx.z == 2) ? Wv : Wp;
    unsigned short* dst = (blockIdx.z < 3) ? wt3 + (size_t)blockIdx.z * 1024 * 1024 : wpt;
    const int k0 = blockIdx.x * 64, n0 = blockIdx.y * 64;
#pragma unroll
    for (int j = 0; j < 4; j++) {
        int row = (tid >> 4) + j * 16;
        int c4 = (tid & 15) * 4;
        float4 v = *(const float4*)&W[(size_t)(k0 + row) * 1024 + n0 + c4];
        t[row][c4 + 0] = f2bf(v.x); t[row][c4 + 1] = f2bf(v.y);
        t[row][c4 + 2] = f2bf(v.z); t[row][c4 + 3] = f2bf(v.w);
    }
    __syncthreads();
#pragma unroll
    for (int j = 0; j < 16; j++) {
        int flat = j * 256 + tid;
        int orow = flat >> 6, ocol = flat & 63;
        dst[(size_t)(n0 + orow) * 1024 + k0 + ocol] = t[ocol][orow];
    }
}

// ---------------------------------------------------------------------------
// Shared 128x128 / BK=32 bf16 MFMA main loop (m97 structure)
// ---------------------------------------------------------------------------
__device__ inline void gemm_mainloop(const unsigned short* __restrict__ A,
                                     const unsigned short* __restrict__ Bt,
                                     unsigned short* As, unsigned short* Bs,
                                     int bm, int bn, int tid, f32x4 (&acc)[4][4]) {
    const int lane = tid & 63, w = tid >> 6;
    const int quad = lane >> 4, cl = lane & 15;
    const int wm = (w >> 1) * 64, wn = (w & 1) * 64;

    auto stage = [&](int k0) {
#pragma unroll
        for (int i = 0; i < 2; i++) {
            int L = tid + i * 256;
            int r = L >> 2;
            int kc = (L & 3) ^ (r & 3);
            gl2lds16(A + (size_t)(bm + r) * 1024 + k0 + kc * 8, &As[L * 8]);
        }
#pragma unroll
        for (int i = 0; i < 2; i++) {
            int L = tid + i * 256;
            int r = L >> 2;
            int kc = (L & 3) ^ (r & 3);
            gl2lds16(Bt + (size_t)(bn + r) * 1024 + k0 + kc * 8, &Bs[L * 8]);
        }
    };

    stage(0);
    __syncthreads();
    for (int k0 = 0;;) {
        bf16x8 af[4], bfr[4];
#pragma unroll
        for (int mt = 0; mt < 4; mt++) {
            int r = wm + mt * 16 + cl;
            af[mt] = *(const bf16x8*)&As[(r * 4 + (quad ^ (r & 3))) * 8];
            int rb = wn + mt * 16 + cl;
            bfr[mt] = *(const bf16x8*)&Bs[(rb * 4 + (quad ^ (rb & 3))) * 8];
        }
#pragma unroll
        for (int mt = 0; mt < 4; mt++)
#pragma unroll
            for (int nt = 0; nt < 4; nt++)
                acc[mt][nt] = __builtin_amdgcn_mfma_f32_16x16x32_bf16(
                    af[mt], bfr[nt], acc[mt][nt], 0, 0, 0);
        k0 += 32;
        if (k0 >= 1024) break;
        __syncthreads();
        stage(k0);
        __syncthreads();
    }
}

// ---------------------------------------------------------------------------
// Fused QKV projection: D[4096, 3072] = xb * wt3^T. Q epilogue folds the
// softmax scale (1/32)*log2(e).
// ---------------------------------------------------------------------------
__global__ __launch_bounds__(256, 2) void gemm_qkv(const unsigned short* __restrict__ A,
                                                   const unsigned short* __restrict__ Bt,
                                                   unsigned short* __restrict__ qb,
                                                   unsigned short* __restrict__ kb,
                                                   unsigned short* __restrict__ vtb) {
    __shared__ unsigned short As[128 * 32];
    __shared__ unsigned short Bs[128 * 32];
    const int tid = threadIdx.x;
    const int bm = blockIdx.y * 128;
    const int bn = blockIdx.x * 128;
    f32x4 acc[4][4] = {};
    gemm_mainloop(A, Bt, As, Bs, bm, bn, tid, acc);

    const int lane = tid & 63, w = tid >> 6;
    const int quad = lane >> 4, cl = lane & 15;
    const int wm = (w >> 1) * 64, wn = (w & 1) * 64;
    const int region = bn >> 10;

    if (region < 2) {
        unsigned short* dst = region ? kb : qb;
        const float qs = region ? 1.0f : 0.045084220027780107f;  // (1/32)*log2e
#pragma unroll
        for (int mt = 0; mt < 4; mt++)
#pragma unroll
            for (int nt = 0; nt < 4; nt++)
#pragma unroll
                for (int rg = 0; rg < 4; rg++) {
                    int m = bm + wm + mt * 16 + quad * 4 + rg;
                    int nn = (bn + wn + nt * 16 + cl) & 1023;
                    int b = m >> 11, t = m & 2047, h = nn >> 6, hs = nn & 63;
                    dst[((size_t)(b * 16 + h) * 2048 + t) * 64 + hs] =
                        f2bf(acc[mt][nt][rg] * qs);
                }
    } else {
#pragma unroll
        for (int mt = 0; mt < 4; mt++) {
            int m0 = bm + wm + mt * 16 + quad * 4;
            int b = m0 >> 11, t0 = m0 & 2047;
#pragma unroll
            for (int nt = 0; nt < 4; nt++) {
                int nn = (bn + wn + nt * 16 + cl) & 1023;
                int h = nn >> 6, hs = nn & 63;
                ushort4 pk;
                pk.x = f2bf(acc[mt][nt][0]); pk.y = f2bf(acc[mt][nt][1]);
                pk.z = f2bf(acc[mt][nt][2]); pk.w = f2bf(acc[mt][nt][3]);
                *(ushort4*)&vtb[((size_t)(b * 16 + h) * 64 + hs) * 2048 + t0] = pk;
            }
        }
    }
}

// ---------------------------------------------------------------------------
// Final projection: out[4096,1024] fp32 = ab * wpt^T + bias. 64x128 tiles.
// ---------------------------------------------------------------------------
__global__ __launch_bounds__(256, 4) void gemm_out(const unsigned short* __restrict__ A,
                                                   const unsigned short* __restrict__ Bt,
                                                   const float* __restrict__ bias,
                                                   float* __restrict__ out) {
    __shared__ unsigned short As[64 * 32];   // 4 KB
    __shared__ unsigned short Bs[128 * 32];  // 8 KB
    const int tid = threadIdx.x;
    const int bm = blockIdx.y * 64;
    const int bn = blockIdx.x * 128;
    const int lane = tid & 63, w = tid >> 6;
    const int quad = lane >> 4, cl = lane & 15;
    const int wm = (w >> 1) * 32, wn = (w & 1) * 64;
    f32x4 acc[2][4] = {};

    auto stage = [&](int k0) {
        {
            int L = tid;
            int r = L >> 2;
            int kc = (L & 3) ^ (r & 3);
            gl2lds16(A + (size_t)(bm + r) * 1024 + k0 + kc * 8, &As[L * 8]);
        }
#pragma unroll
        for (int i = 0; i < 2; i++) {
            int L = tid + i * 256;
            int r = L >> 2;
            int kc = (L & 3) ^ (r & 3);
            gl2lds16(Bt + (size_t)(bn + r) * 1024 + k0 + kc * 8, &Bs[L * 8]);
        }
    };

    stage(0);
    __syncthreads();
    for (int k0 = 0;;) {
        bf16x8 af[2], bfr[4];
#pragma unroll
        for (int mt = 0; mt < 2; mt++) {
            int r = wm + mt * 16 + cl;
            af[mt] = *(const bf16x8*)&As[(r * 4 + (quad ^ (r & 3))) * 8];
        }
#pragma unroll
        for (int nt = 0; nt < 4; nt++) {
            int rb = wn + nt * 16 + cl;
            bfr[nt] = *(const bf16x8*)&Bs[(rb * 4 + (quad ^ (rb & 3))) * 8];
        }
#pragma unroll
        for (int mt = 0; mt < 2; mt++)
#pragma unroll
            for (int nt = 0; nt < 4; nt++)
                acc[mt][nt] = __builtin_amdgcn_mfma_f32_16x16x32_bf16(
                    af[mt], bfr[nt], acc[mt][nt], 0, 0, 0);
        k0 += 32;
        if (k0 >= 1024) break;
        __syncthreads();
        stage(k0);
        __syncthreads();
    }

#pragma unroll
    for (int mt = 0; mt < 2; mt++)
#pragma unroll
        for (int nt = 0; nt < 4; nt++)
#pragma unroll
            for (int rg = 0; rg < 4; rg++) {
                int m = bm + wm + mt * 16 + quad * 4 + rg;
                int n = bn + wn + nt * 16 + cl;
                out[(size_t)m * 1024 + n] = acc[mt][nt][rg] + bias[n];
            }
}

// ---------------------------------------------------------------------------
// MFMA flash attention v4: transposed-S, key-parity split, 4-buffer rotating
// KV with prefetch-before-compute (issue at iteration top, drain at the end
// barrier -> staging latency hidden behind the whole compute phase).
// Block = 4 waves = 64 q-rows. Wave w: parity p=w>>1 (tile 2i+p), qhalf=w&1.
// Tile t lives in buf t&3; bufs written at iter i were last read at iter i-1
// (barrier between) -> no hazard. Fixed-max softmax, additive pair-merge.
// LDS 72KB (K 4x8KB | V 4x8KB | P 8KB) -> 2 blocks/CU.
// ---------------------------------------------------------------------------
__global__ __launch_bounds__(256, 2) void attn_mfma(const unsigned short* __restrict__ qg,
                                                    const unsigned short* __restrict__ kg,
                                                    const unsigned short* __restrict__ vtg,
                                                    unsigned short* __restrict__ og) {
    __shared__ unsigned short lds[36864];  // 72 KB
    // shorts: K bufs 0..16383 (4x4096) | V bufs 16384..32767 | P 32768..36863
    float* Cmb = (float*)lds;              // combine O: [64][stride 68] f32
    float* Ll = (float*)(lds + 8704);      // combine l: 64 f32

    const int tid = threadIdx.x;
    const int idx = blockIdx.x;
    const int bh = idx & 31;
    const int qt = 31 - (idx >> 5);        // 64-row q-tile, longest first
    const int lane = tid & 63, w = tid >> 6;
    const int quad = lane >> 4, cl = lane & 15;
    const int p = w >> 1;                  // k-tile parity this wave handles
    const int qhalf = w & 1;               // which 32 q-rows
    const int qbase = qt * 64;
    const unsigned short* qB = qg + (size_t)bh * 2048 * 64;
    const unsigned short* kB = kg + (size_t)bh * 2048 * 64;
    const unsigned short* vB = vtg + (size_t)bh * 64 * 2048;

    auto stageKV = [&](int kt) {
        unsigned short* Kd = lds + (kt & 3) * 4096;
        unsigned short* Vd = lds + 16384 + (kt & 3) * 4096;
#pragma unroll
        for (int i = 0; i < 2; i++) {
            int L = tid + i * 256;
            int r = L >> 3;
            int kc = (L & 7) ^ (r & 7);
            gl2lds16(kB + (size_t)(kt * 64 + r) * 64 + kc * 8, &Kd[L * 8]);
            gl2lds16(vB + (size_t)r * 2048 + kt * 64 + kc * 8, &Vd[L * 8]);
        }
    };

    // Q fragments straight from global (B-operand layout; 16B loads)
    bf16x8 qf[2][2];
#pragma unroll
    for (int nt2 = 0; nt2 < 2; nt2++)
#pragma unroll
        for (int kf = 0; kf < 2; kf++) {
            int row = qbase + qhalf * 32 + nt2 * 16 + cl;
            qf[nt2][kf] = *(const bf16x8*)&qB[(size_t)row * 64 + (kf * 4 + quad) * 8];
        }

    bf16x8 ones;
#pragma unroll
    for (int i = 0; i < 8; i++) ones[i] = (__bf16)1.0f;

    f32x4 oacc[2][4] = {};
    f32x4 lacc[2] = {};
    unsigned short* Pw = lds + 32768 + w * 1024;  // 32q x 32k per pass
    const int nit = (qt + 2) >> 1;

    stageKV(0);
    if (qt >= 1) stageKV(1);
    __syncthreads();

    for (int i = 0; i < nit; i++) {
        // prefetch next iteration's tiles into the rotating buffers
        if (2 * i + 2 <= qt) stageKV(2 * i + 2);
        if (2 * i + 3 <= qt) stageKV(2 * i + 3);

        const int kt = 2 * i + p;
        if (kt <= qt) {
            const bool diag = (kt == qt);
            const unsigned short* Kl = lds + (kt & 3) * 4096;
            const unsigned short* Vl = lds + 16384 + (kt & 3) * 4096;
            // ---- S^T = K Q^T : rows = 64 keys, cols = 32 q ----
            f32x4 sac[4][2] = {};
#pragma unroll
            for (int kf = 0; kf < 2; kf++)
#pragma unroll
                for (int mt = 0; mt < 4; mt++) {
                    int r = mt * 16 + cl, cc = kf * 4 + quad;
                    bf16x8 kf8 = *(const bf16x8*)&Kl[(r * 8 + (cc ^ (r & 7))) * 8];
#pragma unroll
                    for (int nt2 = 0; nt2 < 2; nt2++)
                        sac[mt][nt2] = __builtin_amdgcn_mfma_f32_16x16x32_bf16(
                            kf8, qf[nt2][kf], sac[mt][nt2], 0, 0, 0);
                }
            // ---- two passes of 32 keys: exp2 + perm-pack P, then PV ----
#pragma unroll
            for (int ks = 0; ks < 2; ks++) {
#pragma unroll
                for (int mtl = 0; mtl < 2; mtl++)
#pragma unroll
                    for (int nt2 = 0; nt2 < 2; nt2++) {
                        float pv[4];
#pragma unroll
                        for (int rg = 0; rg < 4; rg++) {
                            float e = EXP2(sac[ks * 2 + mtl][nt2][rg]);
                            if (diag && (ks * 32 + mtl * 16 + quad * 4 + rg >
                                         nt2 * 16 + cl + qhalf * 32))
                                e = 0.0f;
                            pv[rg] = e;
                        }
                        uint2 d;
                        d.x = pk_bf16(pv[1], pv[0]);  // lo dword: keys +0,+1
                        d.y = pk_bf16(pv[3], pv[2]);  // hi dword: keys +2,+3
                        int r2 = nt2 * 16 + cl;
                        int c = mtl * 2 + (quad >> 1);
                        int pc = c ^ ((r2 >> 1) & 3);
                        *(uint2*)&Pw[r2 * 32 + pc * 8 + (quad & 1) * 4] = d;
                    }
                // PV: O += P V ; l += P.1   (k = 32 keys of this pass)
                bf16x8 pf[2];
#pragma unroll
                for (int mt2 = 0; mt2 < 2; mt2++) {
                    int r2 = mt2 * 16 + cl;
                    int pc = quad ^ ((r2 >> 1) & 3);
                    pf[mt2] = *(const bf16x8*)&Pw[r2 * 32 + pc * 8];
                }
#pragma unroll
                for (int mt2 = 0; mt2 < 2; mt2++)
                    lacc[mt2] = __builtin_amdgcn_mfma_f32_16x16x32_bf16(
                        pf[mt2], ones, lacc[mt2], 0, 0, 0);
#pragma unroll
                for (int nt = 0; nt < 4; nt++) {
                    int r = nt * 16 + cl, cc = ks * 4 + quad;
                    bf16x8 vf = *(const bf16x8*)&Vl[(r * 8 + (cc ^ (r & 7))) * 8];
#pragma unroll
                    for (int mt2 = 0; mt2 < 2; mt2++)
                        oacc[mt2][nt] = __builtin_amdgcn_mfma_f32_16x16x32_bf16(
                            pf[mt2], vf, oacc[mt2][nt], 0, 0, 0);
                }
            }
        }
        __syncthreads();  // drains this iteration's prefetch; syncs buffers
    }

    // ---- pair combine: p=1 writes partials to LDS scratch, p=0 adds ----
    if (p == 1) {
#pragma unroll
        for (int mt2 = 0; mt2 < 2; mt2++)
#pragma unroll
            for (int rg = 0; rg < 4; rg++) {
                int row = qhalf * 32 + mt2 * 16 + quad * 4 + rg;
                if (cl == 0) Ll[row] = lacc[mt2][rg];
#pragma unroll
                for (int nt = 0; nt < 4; nt++)
                    Cmb[row * 68 + nt * 16 + cl] = oacc[mt2][nt][rg];
            }
    }
    __syncthreads();
    if (p == 0) {
        const int b = bh >> 4, h = bh & 15;
#pragma unroll
        for (int mt2 = 0; mt2 < 2; mt2++)
#pragma unroll
            for (int rg = 0; rg < 4; rg++) {
                int row = qhalf * 32 + mt2 * 16 + quad * 4 + rg;
                float inv = 1.0f / (lacc[mt2][rg] + Ll[row]);
                int t = qbase + row;
#pragma unroll
                for (int nt = 0; nt < 4; nt++) {
                    int hs = nt * 16 + cl;
                    float val = oacc[mt2][nt][rg] + Cmb[row * 68 + nt * 16 + cl];
                    og[((size_t)(b * 2048 + t)) * 1024 + h * 64 + hs] = f2bf(val * inv);
                }
            }
    }
}

// ---------------------------------------------------------------------------
extern "C" void kernel_launch(void* const* d_in, const int* in_sizes, int n_in,
                              void* d_out, int out_size, void* d_ws, size_t ws_size,
                              hipStream_t stream) {
    const float* x = (const float*)d_in[0];
    const float* Wq = (const float*)d_in[1];
    const float* Wk = (const float*)d_in[2];
    const float* Wv = (const float*)d_in[3];
    const float* Wp = (const float*)d_in[4];
    const float* bp = (const float*)d_in[5];
    float* out = (float*)d_out;

    unsigned short* xb = (unsigned short*)d_ws;      // 8 MB
    unsigned short* wt3 = xb + (size_t)Mm * Ee;      // 6 MB (Q,K,V transposed)
    unsigned short* wpt = wt3 + (size_t)3 * Ee * Ee; // 2 MB
    unsigned short* qb = wpt + (size_t)Ee * Ee;      // 8 MB each
    unsigned short* kb = qb + (size_t)Mm * Ee;
    unsigned short* vtb = kb + (size_t)Mm * Ee;
    unsigned short* ab = vtb + (size_t)Mm * Ee;

    prep<<<dim3(16, 16, 5), dim3(256), 0, stream>>>(x, Wq, Wk, Wv, Wp, xb, wt3, wpt);
    gemm_qkv<<<dim3(24, 32), dim3(256), 0, stream>>>(xb, wt3, qb, kb, vtb);
    attn_mfma<<<dim3(1024), dim3(256), 0, stream>>>(qb, kb, vtb, ab);
    gemm_out<<<dim3(8, 64), dim3(256), 0, stream>>>(ab, wpt, bp, out);
}